// Round 8
// baseline (978.750 us; speedup 1.0000x reference)
//
#include <hip/hip_runtime.h>

// ---------------------------------------------------------------------------
// TAGCN node regression: 3 TAGConv layers (K=4) + linear head, fp32 math.
// R14: zero-global-atomic CSR build (two-level bucket sort).
// R15: 4-edge quad software-pipelined gather (102->91us per ptag64).
// R16: octet-split gather for F=64 (91->86us). 20KiB LDS = occupancy sweet
// spot (R17's 32KiB halved occupancy, 86->103us).
// R18/R19 NULL (stripped): degree-sorted perm + edge reorder = no change
// (85.5-87us, FETCH back at baseline) -> wave degree-divergence was NOT the
// cost. Perm machinery removed.
// R20: v_fma_mix_f32 gather. Per edge-octet the loop spent ~8 fp16->fp32
// cvts + 2-op weight decode on top of 8 FMAs. VOP3P v_fma_mix_f32 does
// f32 += f16*f16 selecting f16 straight from register halves; weight fed as
// f16 hi-half of (pe>>1) (we packed f2h(nv)<<17, sign-free). ~2x less VALU
// in the gather hot loop; bitwise-identical numerics.
// ---------------------------------------------------------------------------

typedef unsigned long long u64;
typedef unsigned int u32;

__device__ __forceinline__ float h2f(unsigned short u) {
  _Float16 h;
  __builtin_memcpy(&h, &u, 2);
  return (float)h;
}
__device__ __forceinline__ unsigned short f2h(float f) {
  _Float16 h = (_Float16)f;  // RNE
  unsigned short u;
  __builtin_memcpy(&u, &h, 2);
  return u;
}
__device__ __forceinline__ ushort4 pack_h(float4 v) {
  ushort4 r;
  r.x = f2h(v.x); r.y = f2h(v.y); r.z = f2h(v.z); r.w = f2h(v.w);
  return r;
}
__device__ __forceinline__ float4 unpack_h(ushort4 u) {
  return make_float4(h2f(u.x), h2f(u.y), h2f(u.z), h2f(u.w));
}

// fma_mix helpers: acc += f16(hi of wsh) * f16(lo/hi of h)   [fp32 FMA]
__device__ __forceinline__ void fmix_lo(float& acc, u32 wsh, u32 h) {
  asm("v_fma_mix_f32 %0, %1, %2, %0 op_sel:[1,0,0] op_sel_hi:[1,1,0]"
      : "+v"(acc) : "v"(wsh), "v"(h));
}
__device__ __forceinline__ void fmix_hi(float& acc, u32 wsh, u32 h) {
  asm("v_fma_mix_f32 %0, %1, %2, %0 op_sel:[1,1,0] op_sel_hi:[1,1,0]"
      : "+v"(acc) : "v"(wsh), "v"(h));
}

// ---------------- atomic-free CSR build ----------------
// coarse bucket = dst >> 7 (128 nodes/bucket). NB <= 1024 (N <= 131072).
// item u64 = [0:8][w_f32:32][dst_low7:7][src:17]

__global__ __launch_bounds__(256) void k_hist(const int* __restrict__ dst, u32* __restrict__ H,
                                              int E, int CH, int NB,
                                              const float4* __restrict__ x4,
                                              ushort4* __restrict__ xh, int n4) {
  __shared__ u32 hc[1024];
  int tid = threadIdx.x, blk = blockIdx.x, nblk = gridDim.x;
  for (int i = tid; i < 1024; i += 256) hc[i] = 0;
  for (int i = blk * 256 + tid; i < n4; i += nblk * 256) xh[i] = pack_h(x4[i]);
  __syncthreads();
  int e0 = blk * CH, e1 = min(E, e0 + CH);
  for (int e = e0 + tid; e < e1; e += 256) atomicAdd(&hc[((u32)dst[e]) >> 7], 1u);
  __syncthreads();
  for (int c = tid; c < NB; c += 256) H[(size_t)c * nblk + blk] = hc[c];
}

__global__ void scanH_blocks(u32* __restrict__ H, u32* __restrict__ bsum, int n) {
  __shared__ u32 s[256];
  int tid = threadIdx.x;
  int i = blockIdx.x * 256 + tid;
  u32 v = (i < n) ? H[i] : 0;
  s[tid] = v;
  __syncthreads();
#pragma unroll
  for (int off = 1; off < 256; off <<= 1) {
    u32 t = (tid >= off) ? s[tid - off] : 0;
    __syncthreads();
    s[tid] += t;
    __syncthreads();
  }
  if (i < n) H[i] = s[tid] - v;
  if (tid == 255) bsum[blockIdx.x] = s[255];
}

__global__ void scanH_sums(u32* __restrict__ bsum, int nb) {
  __shared__ u32 s[1024];
  int tid = threadIdx.x;
  u32 v = (tid < nb) ? bsum[tid] : 0;
  s[tid] = v;
  __syncthreads();
#pragma unroll
  for (int off = 1; off < 1024; off <<= 1) {
    u32 t = (tid >= off) ? s[tid - off] : 0;
    __syncthreads();
    s[tid] += t;
    __syncthreads();
  }
  if (tid < nb) bsum[tid] = s[tid] - v;
}

__global__ void scanH_add(u32* __restrict__ H, const u32* __restrict__ bsum, int n) {
  int i = blockIdx.x * blockDim.x + threadIdx.x;
  if (i < n) H[i] += bsum[i >> 8];
}

__global__ __launch_bounds__(256) void k_scatter(const int* __restrict__ src,
                                                 const int* __restrict__ dst,
                                                 const float* __restrict__ w,
                                                 const u32* __restrict__ H,
                                                 u64* __restrict__ sorted, int E, int CH, int NB) {
  __shared__ u32 cur[1024];
  int tid = threadIdx.x, blk = blockIdx.x, nblk = gridDim.x;
  for (int c = tid; c < NB; c += 256) cur[c] = H[(size_t)c * nblk + blk];
  __syncthreads();
  int e0 = blk * CH, e1 = min(E, e0 + CH);
  for (int e = e0 + tid; e < e1; e += 256) {
    int d = dst[e];
    int c = ((u32)d) >> 7;
    u32 p = atomicAdd(&cur[c], 1u);
    u64 it = (u64)(u32)src[e] | ((u64)((u32)d & 127u) << 17) |
             ((u64)__float_as_uint(w[e]) << 24);
    sorted[p] = it;
  }
}

#define BCAP 6144
__global__ __launch_bounds__(256) void k_bucket(u64* __restrict__ sorted,
                                                const u32* __restrict__ H, int NBLK,
                                                int* __restrict__ ptr, float* __restrict__ dinv,
                                                int N, int E, int NB) {
  __shared__ u64 stage[BCAP];
  __shared__ u32 cnt[128], base[128], cur[128], tmp[128];
  __shared__ float ws[128];
  int c = blockIdx.x, tid = threadIdx.x;
  int b0 = (int)H[(size_t)c * NBLK];
  int b1 = (c + 1 < NB) ? (int)H[(size_t)(c + 1) * NBLK] : E;
  int m = b1 - b0;
  if (tid < 128) { cnt[tid] = 0; ws[tid] = 0.f; }
  __syncthreads();
  for (int i = tid; i < m; i += 256) {
    u64 it = sorted[b0 + i];
    stage[i] = it;
    int lo = (int)((it >> 17) & 127u);
    atomicAdd(&cnt[lo], 1u);
    atomicAdd(&ws[lo], __uint_as_float((u32)(it >> 24)));
  }
  __syncthreads();
  u32 v = (tid < 128) ? cnt[tid] : 0;
  if (tid < 128) tmp[tid] = v;
  __syncthreads();
#pragma unroll
  for (int off = 1; off < 128; off <<= 1) {
    u32 t = 0;
    if (tid < 128 && tid >= off) t = tmp[tid - off];
    __syncthreads();
    if (tid < 128) tmp[tid] += t;
    __syncthreads();
  }
  if (tid < 128) {
    base[tid] = tmp[tid] - v;
    cur[tid] = tmp[tid] - v;
    int node = c * 128 + tid;
    if (node < N) {
      ptr[node] = b0 + (int)base[tid];
      float d = ws[tid];
      dinv[node] = (d > 0.f) ? rsqrtf(fmaxf(d, 1e-30f)) : 0.f;
    }
  }
  if (c == NB - 1 && tid == 0) ptr[N] = E;
  __syncthreads();
  for (int i = tid; i < m; i += 256) {
    u64 it = stage[i];
    int lo = (int)((it >> 17) & 127u);
    u32 p = atomicAdd(&cur[lo], 1u);
    sorted[b0 + (int)p] = it;
  }
}

__global__ __launch_bounds__(256) void k_pack(const u64* __restrict__ sorted,
                                              const float* __restrict__ dinv,
                                              const u32* __restrict__ H, int NBLK,
                                              u32* __restrict__ ep, int E, int NB) {
  int c = blockIdx.x;
  int b0 = (int)H[(size_t)c * NBLK];
  int b1 = (c + 1 < NB) ? (int)H[(size_t)(c + 1) * NBLK] : E;
  for (int i = b0 + threadIdx.x; i < b1; i += 256) {
    u64 it = sorted[i];
    int s = (int)(it & 0x1FFFFu);
    int dn = c * 128 + (int)((it >> 17) & 127u);
    float wv = __uint_as_float((u32)(it >> 24));
    float nv = dinv[s] * wv * dinv[dn];
    ep[i] = ((u32)f2h(nv) << 17) | (u32)s;
  }
}

// ---- R15 gather (4-edge quads, pipelined) + R20 fma_mix: ptag16 path ----
// hh = two fp16 features in one u32 (lo = feature 2f, hi = 2f+1)
__device__ __forceinline__ void acc_e2(float4& a, u32 pe, uint2 hh) {
  u32 wsh = pe >> 1;  // hi-half = fp16 weight pattern (sign-free pack)
  fmix_lo(a.x, wsh, hh.x); fmix_hi(a.y, wsh, hh.x);
  fmix_lo(a.z, wsh, hh.y); fmix_hi(a.w, wsh, hh.y);
}

template <int F4>
__device__ __forceinline__ float4 gather(const int* __restrict__ ptr, const u32* __restrict__ ep,
                                         const ushort4* __restrict__ hin, int node, int f4) {
  int e0 = ptr[node], e1 = ptr[node + 1];
  float4 a = make_float4(0.f, 0.f, 0.f, 0.f);
  int e = e0;
  while (e < e1 && (e & 3)) {
    u32 pe = ep[e];
    acc_e2(a, pe, *(const uint2*)(hin + ((u32)(pe & 0x1FFFFu) * F4 + f4)));
    ++e;
  }
  int nq = (e1 - e) >> 2;
  if (nq > 0) {
    uint4 p = *(const uint4*)(ep + e);
    uint2 h0 = *(const uint2*)(hin + ((u32)(p.x & 0x1FFFFu) * F4 + f4));
    uint2 h1 = *(const uint2*)(hin + ((u32)(p.y & 0x1FFFFu) * F4 + f4));
    uint2 h2 = *(const uint2*)(hin + ((u32)(p.z & 0x1FFFFu) * F4 + f4));
    uint2 h3 = *(const uint2*)(hin + ((u32)(p.w & 0x1FFFFu) * F4 + f4));
    for (int q = 1; q < nq; ++q) {
      uint4 pn = *(const uint4*)(ep + e + 4 * q);
      uint2 g0 = *(const uint2*)(hin + ((u32)(pn.x & 0x1FFFFu) * F4 + f4));
      uint2 g1 = *(const uint2*)(hin + ((u32)(pn.y & 0x1FFFFu) * F4 + f4));
      uint2 g2 = *(const uint2*)(hin + ((u32)(pn.z & 0x1FFFFu) * F4 + f4));
      uint2 g3 = *(const uint2*)(hin + ((u32)(pn.w & 0x1FFFFu) * F4 + f4));
      acc_e2(a, p.x, h0); acc_e2(a, p.y, h1);
      acc_e2(a, p.z, h2); acc_e2(a, p.w, h3);
      p = pn; h0 = g0; h1 = g1; h2 = g2; h3 = g3;
    }
    acc_e2(a, p.x, h0); acc_e2(a, p.y, h1);
    acc_e2(a, p.z, h2); acc_e2(a, p.w, h3);
    e += nq * 4;
  }
  while (e < e1) {
    u32 pe = ep[e];
    acc_e2(a, pe, *(const uint2*)(hin + ((u32)(pe & 0x1FFFFu) * F4 + f4)));
    ++e;
  }
  return a;
}

// ---- R16 octet gather + R20 fma_mix, F=64: 8 lanes x 8 features ----
__device__ __forceinline__ void acc8(float4& a0, float4& a1, u32 pe, uint4 r) {
  u32 wsh = pe >> 1;  // hi-half = fp16 weight
  fmix_lo(a0.x, wsh, r.x); fmix_hi(a0.y, wsh, r.x);
  fmix_lo(a0.z, wsh, r.y); fmix_hi(a0.w, wsh, r.y);
  fmix_lo(a1.x, wsh, r.z); fmix_hi(a1.y, wsh, r.z);
  fmix_lo(a1.z, wsh, r.w); fmix_hi(a1.w, wsh, r.w);
}

__device__ __forceinline__ void gather64o(const int* __restrict__ ptr, const u32* __restrict__ ep,
                                          const ushort4* __restrict__ hin, int node,
                                          int f8, int o, float4& a0, float4& a1) {
  int e0 = ptr[node], e1 = ptr[node + 1];
  const u32 foff = 2u * (u32)f8;
  int e = e0;
  while (e < e1 && (e & 3)) {
    if ((e & 1) == o) {
      u32 pe = ep[e];
      uint4 r = *(const uint4*)(hin + ((u32)(pe & 0x1FFFFu) * 16u + foff));
      acc8(a0, a1, pe, r);
    }
    ++e;
  }
  int nq = (e1 - e) >> 2;
  int q = o;
  if (q < nq) {
    uint4 p = *(const uint4*)(ep + e + 4 * q);
    uint4 r0 = *(const uint4*)(hin + ((u32)(p.x & 0x1FFFFu) * 16u + foff));
    uint4 r1 = *(const uint4*)(hin + ((u32)(p.y & 0x1FFFFu) * 16u + foff));
    for (;;) {
      uint4 r2 = *(const uint4*)(hin + ((u32)(p.z & 0x1FFFFu) * 16u + foff));
      uint4 r3 = *(const uint4*)(hin + ((u32)(p.w & 0x1FFFFu) * 16u + foff));
      acc8(a0, a1, p.x, r0);
      acc8(a0, a1, p.y, r1);
      int qn = q + 2;
      if (qn >= nq) {
        acc8(a0, a1, p.z, r2);
        acc8(a0, a1, p.w, r3);
        break;
      }
      uint4 pn = *(const uint4*)(ep + e + 4 * qn);
      r0 = *(const uint4*)(hin + ((u32)(pn.x & 0x1FFFFu) * 16u + foff));
      r1 = *(const uint4*)(hin + ((u32)(pn.y & 0x1FFFFu) * 16u + foff));
      acc8(a0, a1, p.z, r2);
      acc8(a0, a1, p.w, r3);
      p = pn; q = qn;
    }
  }
  e += nq * 4;
  while (e < e1) {
    if ((e & 1) == o) {
      u32 pe = ep[e];
      uint4 r = *(const uint4*)(hin + ((u32)(pe & 0x1FFFFu) * 16u + foff));
      acc8(a0, a1, pe, r);
    }
    ++e;
  }
}

// scalar-broadcast mm accumulate: a += t(slot ln) @ W  (R6's 28-VGPR shape).
// Tile rows are WAVE-PRIVATE (ln = tid>>4): same-wave LDS RAW needs no barrier.
__device__ __forceinline__ void mm_acc(const float* __restrict__ tl, const float4* __restrict__ Wl,
                                       int ln, int j4, float4& a) {
#pragma unroll 8
  for (int i = 0; i < 64; ++i) {
    float tv = tl[ln * 64 + ((((i >> 2) ^ ln) << 2) | (i & 3))];
    float4 wv = Wl[i * 16 + j4];
    a.x = fmaf(tv, wv.x, a.x); a.y = fmaf(tv, wv.y, a.y);
    a.z = fmaf(tv, wv.z, a.z); a.w = fmaf(tv, wv.w, a.w);
  }
}

// ---------- fused prop + matmul, F=64 (R16 octet gather) ----------
template <bool FIRST, bool LAST, bool HEAD>
__launch_bounds__(256)
__global__ void ptag64_k(const int* __restrict__ ptr, const u32* __restrict__ ep,
                         const ushort4* __restrict__ hin, ushort4* __restrict__ hout,
                         const float4* __restrict__ Wk4, const float4* __restrict__ W04,
                         ushort4* __restrict__ acch, const float4* __restrict__ bias4,
                         const float* __restrict__ Wout, const float* __restrict__ bout,
                         float* __restrict__ outv, int n) {
  __shared__ float4 Wl[1024];
  __shared__ float4 tl4[256];
  const float* tl = (const float*)tl4;
  int tid = threadIdx.x;
  for (int i = tid; i < 1024; i += 256) Wl[i] = Wk4[i];
  int gid = blockIdx.x * 256 + tid;
  int node = gid >> 4, j4 = gid & 15, ln = tid >> 4;
  const int o = j4 >> 3, f8 = j4 & 7;

  float4 a0 = make_float4(0.f, 0.f, 0.f, 0.f);
  float4 a1 = make_float4(0.f, 0.f, 0.f, 0.f);
  if (node < n) gather64o(ptr, ep, hin, node, f8, o, a0, a1);
  // cross-octet combine: partner lane is j4^8 within the 16-lane group
  a0.x += __shfl_xor(a0.x, 8, 16); a0.y += __shfl_xor(a0.y, 8, 16);
  a0.z += __shfl_xor(a0.z, 8, 16); a0.w += __shfl_xor(a0.w, 8, 16);
  a1.x += __shfl_xor(a1.x, 8, 16); a1.y += __shfl_xor(a1.y, 8, 16);
  a1.z += __shfl_xor(a1.z, 8, 16); a1.w += __shfl_xor(a1.w, 8, 16);
  // lane (o,f8) owns float4-group g = 2*f8+o (features 8*f8+4*o ..+4)
  float4 t = (o == 0) ? a0 : a1;
  int g = 2 * f8 + o;
  if (node < n && !LAST) hout[(size_t)node * 16 + g] = pack_h(t);
  tl4[ln * 16 + (g ^ ln)] = t;
  __syncthreads();

  float4 a = make_float4(0.f, 0.f, 0.f, 0.f);
  if (!FIRST && node < n) a = unpack_h(acch[(size_t)node * 16 + j4]);
  mm_acc(tl, Wl, ln, j4, a);
  if (FIRST) {
    __syncthreads();
    for (int i = tid; i < 1024; i += 256) Wl[i] = W04[i];
    float4 own = make_float4(0.f, 0.f, 0.f, 0.f);
    if (node < n) own = unpack_h(hin[(size_t)node * 16 + j4]);
    tl4[ln * 16 + (j4 ^ ln)] = own;
    __syncthreads();
    mm_acc(tl, Wl, ln, j4, a);
  }
  if (node >= n) return;

  if (LAST) {
    float4 b = bias4[j4];
    a.x += b.x; a.y += b.y; a.z += b.z; a.w += b.w;
    a.x = (a.x >= 0.f) ? a.x : 0.01f * a.x;
    a.y = (a.y >= 0.f) ? a.y : 0.01f * a.y;
    a.z = (a.z >= 0.f) ? a.z : 0.01f * a.z;
    a.w = (a.w >= 0.f) ? a.w : 0.01f * a.w;
    if (HEAD) {
      float v = a.x * Wout[4 * j4] + a.y * Wout[4 * j4 + 1] +
                a.z * Wout[4 * j4 + 2] + a.w * Wout[4 * j4 + 3];
      v += __shfl_down(v, 8, 16);
      v += __shfl_down(v, 4, 16);
      v += __shfl_down(v, 2, 16);
      v += __shfl_down(v, 1, 16);
      if (j4 == 0) outv[node] = v + bout[0];
    } else {
      hout[(size_t)node * 16 + j4] = pack_h(a);
    }
  } else {
    acch[(size_t)node * 16 + j4] = pack_h(a);
  }
}

// ---------- fused prop + matmul, layer 1: F_in=16 (4 lanes/node) ----------
template <bool FIRST, bool LAST>
__launch_bounds__(256)
__global__ void ptag16_k(const int* __restrict__ ptr, const u32* __restrict__ ep,
                         const ushort4* __restrict__ hin, ushort4* __restrict__ hout,
                         const float4* __restrict__ Wk4, const float4* __restrict__ W04,
                         ushort4* __restrict__ acch, const float4* __restrict__ bias4,
                         ushort4* __restrict__ outbuf, int n) {
  __shared__ float4 Wl[256];
  __shared__ float4 W0l[FIRST ? 256 : 1];
  __shared__ float4 tl4[64 * 5];
  const float* tl = (const float*)tl4;
  int tid = threadIdx.x;
  Wl[tid] = Wk4[tid];
  if (FIRST) W0l[tid] = W04[tid];
  int gid = blockIdx.x * 256 + tid;
  int node = gid >> 2, q = tid & 3, ln = tid >> 2;

  float4 t = make_float4(0.f, 0.f, 0.f, 0.f);
  if (node < n) {
    t = gather<4>(ptr, ep, hin, node, q);
    if (!LAST) hout[(size_t)node * 4 + q] = pack_h(t);
  }
  tl4[ln * 5 + q] = t;
  __syncthreads();

  float4 a[4];
#pragma unroll
  for (int c = 0; c < 4; ++c) a[c] = make_float4(0.f, 0.f, 0.f, 0.f);
  if (!FIRST && node < n) {
#pragma unroll
    for (int c = 0; c < 4; ++c) a[c] = unpack_h(acch[(size_t)node * 16 + 4 * q + c]);
  }
#pragma unroll 4
  for (int i = 0; i < 16; ++i) {
    float tv = tl[ln * 20 + i];
#pragma unroll
    for (int c = 0; c < 4; ++c) {
      float4 wv = Wl[i * 16 + 4 * q + c];
      a[c].x = fmaf(tv, wv.x, a[c].x); a[c].y = fmaf(tv, wv.y, a[c].y);
      a[c].z = fmaf(tv, wv.z, a[c].z); a[c].w = fmaf(tv, wv.w, a[c].w);
    }
  }
  if (FIRST) {
    __syncthreads();
    float4 own = make_float4(0.f, 0.f, 0.f, 0.f);
    if (node < n) own = unpack_h(hin[(size_t)node * 4 + q]);
    tl4[ln * 5 + q] = own;
    __syncthreads();
#pragma unroll 4
    for (int i = 0; i < 16; ++i) {
      float tv = tl[ln * 20 + i];
#pragma unroll
      for (int c = 0; c < 4; ++c) {
        float4 wv = W0l[i * 16 + 4 * q + c];
        a[c].x = fmaf(tv, wv.x, a[c].x); a[c].y = fmaf(tv, wv.y, a[c].y);
        a[c].z = fmaf(tv, wv.z, a[c].z); a[c].w = fmaf(tv, wv.w, a[c].w);
      }
    }
  }
  if (node >= n) return;

  if (LAST) {
#pragma unroll
    for (int c = 0; c < 4; ++c) {
      float4 b = bias4[4 * q + c];
      a[c].x += b.x; a[c].y += b.y; a[c].z += b.z; a[c].w += b.w;
      a[c].x = (a[c].x >= 0.f) ? a[c].x : 0.01f * a[c].x;
      a[c].y = (a[c].y >= 0.f) ? a[c].y : 0.01f * a[c].y;
      a[c].z = (a[c].z >= 0.f) ? a[c].z : 0.01f * a[c].z;
      a[c].w = (a[c].w >= 0.f) ? a[c].w : 0.01f * a[c].w;
      outbuf[(size_t)node * 16 + 4 * q + c] = pack_h(a[c]);
    }
  } else {
#pragma unroll
    for (int c = 0; c < 4; ++c) acch[(size_t)node * 16 + 4 * q + c] = pack_h(a[c]);
  }
}

extern "C" void kernel_launch(void* const* d_in, const int* in_sizes, int n_in,
                              void* d_out, int out_size, void* d_ws, size_t ws_size,
                              hipStream_t stream) {
  const float* x    = (const float*)d_in[0];
  const int*   ei   = (const int*)d_in[1];
  const float* ew   = (const float*)d_in[2];
  const float* W1   = (const float*)d_in[4];
  const float* b1   = (const float*)d_in[5];
  const float* W2   = (const float*)d_in[6];
  const float* b2   = (const float*)d_in[7];
  const float* Wout = (const float*)d_in[8];
  const float* bout = (const float*)d_in[9];
  float* out = (float*)d_out;

  const int N = in_sizes[0] / 16;
  const int E = in_sizes[2];
  const int* src = ei;
  const int* dst = ei + E;

  const int NBLK = 256;
  const int CH = (E + NBLK - 1) / NBLK;
  const int NB = (N + 127) >> 7;
  const int HN = NB * NBLK;

  char* ws = (char*)d_ws;
  size_t off = 0;
  auto alloc = [&](size_t bytes) {
    char* p = ws + off;
    off = (off + bytes + 255) & ~(size_t)255;
    return p;
  };
  u32*     H      = (u32*)alloc((size_t)HN * 4);
  u32*     bsum   = (u32*)alloc(4096);
  float*   dinv   = (float*)alloc((size_t)N * 4);
  int*     ptr    = (int*)alloc(((size_t)N + 1) * 4);
  u64*     sorted = (u64*)alloc((size_t)E * 8);
  u32*     ep     = (u32*)alloc((size_t)E * 4);
  ushort4* xh     = (ushort4*)alloc((size_t)N * 16 * 2);
  ushort4* hb0    = (ushort4*)alloc((size_t)N * 64 * 2);
  ushort4* hb1    = (ushort4*)alloc((size_t)N * 64 * 2);
  ushort4* hb2    = (ushort4*)alloc((size_t)N * 64 * 2);
  ushort4* acch   = (ushort4*)alloc((size_t)N * 64 * 2);

  // ---- atomic-free CSR build ----
  k_hist<<<NBLK, 256, 0, stream>>>(dst, H, E, CH, NB, (const float4*)x, xh, N * 4);
  scanH_blocks<<<HN / 256, 256, 0, stream>>>(H, bsum, HN);
  scanH_sums<<<1, 1024, 0, stream>>>(bsum, HN / 256);
  scanH_add<<<HN / 256, 256, 0, stream>>>(H, bsum, HN);
  k_scatter<<<NBLK, 256, 0, stream>>>(src, dst, ew, H, sorted, E, CH, NB);
  k_bucket<<<NB, 256, 0, stream>>>(sorted, H, NBLK, ptr, dinv, N, E, NB);
  k_pack<<<NB, 256, 0, stream>>>(sorted, dinv, H, NBLK, ep, E, NB);

  int g4  = (N * 4 + 255) / 256;   // layer-1 fused (4 lanes/node)
  int g16 = (N * 16 + 255) / 256;  // F=64 fused

  auto W1k = [&](int k) { return (const float4*)(W1 + (size_t)k * 1024); };
  auto W2k = [&](int l, int k) { return (const float4*)(W2 + ((size_t)l * 5 + k) * 4096); };

  // ---- Layer 1 (16 -> 64): acc in acch, t ping-pong hb0/hb1, h1 -> hb2 ----
  ptag16_k<true,  false><<<g4, 256, 0, stream>>>(ptr, ep, xh,  hb0, W1k(1), W1k(0), acch, nullptr, nullptr, N);
  ptag16_k<false, false><<<g4, 256, 0, stream>>>(ptr, ep, hb0, hb1, W1k(2), nullptr, acch, nullptr, nullptr, N);
  ptag16_k<false, false><<<g4, 256, 0, stream>>>(ptr, ep, hb1, hb0, W1k(3), nullptr, acch, nullptr, nullptr, N);
  ptag16_k<false, true ><<<g4, 256, 0, stream>>>(ptr, ep, hb0, nullptr, W1k(4), nullptr, acch,
                                                 (const float4*)b1, hb2, N);

  // ---- Layers 2+3 + head: R16 fused kernels (proven 20KiB-LDS shape) ----
  ptag64_k<true,  false, false><<<g16, 256, 0, stream>>>(ptr, ep, hb2, hb0, W2k(0,1), W2k(0,0), acch,
                                                         nullptr, nullptr, nullptr, nullptr, N);
  ptag64_k<false, false, false><<<g16, 256, 0, stream>>>(ptr, ep, hb0, hb1, W2k(0,2), nullptr, acch,
                                                         nullptr, nullptr, nullptr, nullptr, N);
  ptag64_k<false, false, false><<<g16, 256, 0, stream>>>(ptr, ep, hb1, hb0, W2k(0,3), nullptr, acch,
                                                         nullptr, nullptr, nullptr, nullptr, N);
  ptag64_k<false, true,  false><<<g16, 256, 0, stream>>>(ptr, ep, hb0, hb2, W2k(0,4), nullptr, acch,
                                                         (const float4*)b2, nullptr, nullptr, nullptr, N);
  ptag64_k<true,  false, false><<<g16, 256, 0, stream>>>(ptr, ep, hb2, hb0, W2k(1,1), W2k(1,0), acch,
                                                         nullptr, nullptr, nullptr, nullptr, N);
  ptag64_k<false, false, false><<<g16, 256, 0, stream>>>(ptr, ep, hb0, hb1, W2k(1,2), nullptr, acch,
                                                         nullptr, nullptr, nullptr, nullptr, N);
  ptag64_k<false, false, false><<<g16, 256, 0, stream>>>(ptr, ep, hb1, hb0, W2k(1,3), nullptr, acch,
                                                         nullptr, nullptr, nullptr, nullptr, N);
  ptag64_k<false, true,  true ><<<g16, 256, 0, stream>>>(ptr, ep, hb0, nullptr, W2k(1,4), nullptr, acch,
                                                         (const float4*)(b2 + 64), Wout, bout, out, N);
}

// Round 9
// 940.799 us; speedup vs baseline: 1.0403x; 1.0403x over previous
//
#include <hip/hip_runtime.h>

// ---------------------------------------------------------------------------
// TAGCN node regression: 3 TAGConv layers (K=4) + linear head, fp32 math.
// R14: zero-global-atomic CSR build (two-level bucket sort).
// R15: 4-edge quad software-pipelined gather (102->91us per ptag64).
// R16: octet-split gather for F=64 (91->86us). 20KiB LDS = occupancy sweet
// spot (R17's 32KiB halved occupancy; 64-VGPR boundary is the same cliff).
// R18/R19 NULL (stripped): degree divergence was not the cost.
// R20: v_fma_mix_f32 gather (VALU -30%, dur 86->84) -> VALU not binding.
// R21: bank ping-pong full-quad prefetch. VGPR=32 showed the compiler
// register-minimized the pipeline: rows were issued only ~half a quad
// (~2 acc8) before use -> exposed L2/L3 latency = the 37% issue-stall.
// New loop alternates two register banks (A/B), unrolled x2 (zero rotation
// movs): while ACC-ing bank A, bank B's ep+4 rows are in flight; every row
// has a full quad (4 acc8) of cover. __launch_bounds__(256,8) guards the
// 64-VGPR occupancy cliff. ptag16/CSR unchanged.
// ---------------------------------------------------------------------------

typedef unsigned long long u64;
typedef unsigned int u32;

__device__ __forceinline__ float h2f(unsigned short u) {
  _Float16 h;
  __builtin_memcpy(&h, &u, 2);
  return (float)h;
}
__device__ __forceinline__ unsigned short f2h(float f) {
  _Float16 h = (_Float16)f;  // RNE
  unsigned short u;
  __builtin_memcpy(&u, &h, 2);
  return u;
}
__device__ __forceinline__ ushort4 pack_h(float4 v) {
  ushort4 r;
  r.x = f2h(v.x); r.y = f2h(v.y); r.z = f2h(v.z); r.w = f2h(v.w);
  return r;
}
__device__ __forceinline__ float4 unpack_h(ushort4 u) {
  return make_float4(h2f(u.x), h2f(u.y), h2f(u.z), h2f(u.w));
}

// fma_mix helpers: acc += f16(hi of wsh) * f16(lo/hi of h)   [fp32 FMA]
__device__ __forceinline__ void fmix_lo(float& acc, u32 wsh, u32 h) {
  asm("v_fma_mix_f32 %0, %1, %2, %0 op_sel:[1,0,0] op_sel_hi:[1,1,0]"
      : "+v"(acc) : "v"(wsh), "v"(h));
}
__device__ __forceinline__ void fmix_hi(float& acc, u32 wsh, u32 h) {
  asm("v_fma_mix_f32 %0, %1, %2, %0 op_sel:[1,1,0] op_sel_hi:[1,1,0]"
      : "+v"(acc) : "v"(wsh), "v"(h));
}

// ---------------- atomic-free CSR build ----------------
// coarse bucket = dst >> 7 (128 nodes/bucket). NB <= 1024 (N <= 131072).
// item u64 = [0:8][w_f32:32][dst_low7:7][src:17]

__global__ __launch_bounds__(256) void k_hist(const int* __restrict__ dst, u32* __restrict__ H,
                                              int E, int CH, int NB,
                                              const float4* __restrict__ x4,
                                              ushort4* __restrict__ xh, int n4) {
  __shared__ u32 hc[1024];
  int tid = threadIdx.x, blk = blockIdx.x, nblk = gridDim.x;
  for (int i = tid; i < 1024; i += 256) hc[i] = 0;
  for (int i = blk * 256 + tid; i < n4; i += nblk * 256) xh[i] = pack_h(x4[i]);
  __syncthreads();
  int e0 = blk * CH, e1 = min(E, e0 + CH);
  for (int e = e0 + tid; e < e1; e += 256) atomicAdd(&hc[((u32)dst[e]) >> 7], 1u);
  __syncthreads();
  for (int c = tid; c < NB; c += 256) H[(size_t)c * nblk + blk] = hc[c];
}

__global__ void scanH_blocks(u32* __restrict__ H, u32* __restrict__ bsum, int n) {
  __shared__ u32 s[256];
  int tid = threadIdx.x;
  int i = blockIdx.x * 256 + tid;
  u32 v = (i < n) ? H[i] : 0;
  s[tid] = v;
  __syncthreads();
#pragma unroll
  for (int off = 1; off < 256; off <<= 1) {
    u32 t = (tid >= off) ? s[tid - off] : 0;
    __syncthreads();
    s[tid] += t;
    __syncthreads();
  }
  if (i < n) H[i] = s[tid] - v;
  if (tid == 255) bsum[blockIdx.x] = s[255];
}

__global__ void scanH_sums(u32* __restrict__ bsum, int nb) {
  __shared__ u32 s[1024];
  int tid = threadIdx.x;
  u32 v = (tid < nb) ? bsum[tid] : 0;
  s[tid] = v;
  __syncthreads();
#pragma unroll
  for (int off = 1; off < 1024; off <<= 1) {
    u32 t = (tid >= off) ? s[tid - off] : 0;
    __syncthreads();
    s[tid] += t;
    __syncthreads();
  }
  if (tid < nb) bsum[tid] = s[tid] - v;
}

__global__ void scanH_add(u32* __restrict__ H, const u32* __restrict__ bsum, int n) {
  int i = blockIdx.x * blockDim.x + threadIdx.x;
  if (i < n) H[i] += bsum[i >> 8];
}

__global__ __launch_bounds__(256) void k_scatter(const int* __restrict__ src,
                                                 const int* __restrict__ dst,
                                                 const float* __restrict__ w,
                                                 const u32* __restrict__ H,
                                                 u64* __restrict__ sorted, int E, int CH, int NB) {
  __shared__ u32 cur[1024];
  int tid = threadIdx.x, blk = blockIdx.x, nblk = gridDim.x;
  for (int c = tid; c < NB; c += 256) cur[c] = H[(size_t)c * nblk + blk];
  __syncthreads();
  int e0 = blk * CH, e1 = min(E, e0 + CH);
  for (int e = e0 + tid; e < e1; e += 256) {
    int d = dst[e];
    int c = ((u32)d) >> 7;
    u32 p = atomicAdd(&cur[c], 1u);
    u64 it = (u64)(u32)src[e] | ((u64)((u32)d & 127u) << 17) |
             ((u64)__float_as_uint(w[e]) << 24);
    sorted[p] = it;
  }
}

#define BCAP 6144
__global__ __launch_bounds__(256) void k_bucket(u64* __restrict__ sorted,
                                                const u32* __restrict__ H, int NBLK,
                                                int* __restrict__ ptr, float* __restrict__ dinv,
                                                int N, int E, int NB) {
  __shared__ u64 stage[BCAP];
  __shared__ u32 cnt[128], base[128], cur[128], tmp[128];
  __shared__ float ws[128];
  int c = blockIdx.x, tid = threadIdx.x;
  int b0 = (int)H[(size_t)c * NBLK];
  int b1 = (c + 1 < NB) ? (int)H[(size_t)(c + 1) * NBLK] : E;
  int m = b1 - b0;
  if (tid < 128) { cnt[tid] = 0; ws[tid] = 0.f; }
  __syncthreads();
  for (int i = tid; i < m; i += 256) {
    u64 it = sorted[b0 + i];
    stage[i] = it;
    int lo = (int)((it >> 17) & 127u);
    atomicAdd(&cnt[lo], 1u);
    atomicAdd(&ws[lo], __uint_as_float((u32)(it >> 24)));
  }
  __syncthreads();
  u32 v = (tid < 128) ? cnt[tid] : 0;
  if (tid < 128) tmp[tid] = v;
  __syncthreads();
#pragma unroll
  for (int off = 1; off < 128; off <<= 1) {
    u32 t = 0;
    if (tid < 128 && tid >= off) t = tmp[tid - off];
    __syncthreads();
    if (tid < 128) tmp[tid] += t;
    __syncthreads();
  }
  if (tid < 128) {
    base[tid] = tmp[tid] - v;
    cur[tid] = tmp[tid] - v;
    int node = c * 128 + tid;
    if (node < N) {
      ptr[node] = b0 + (int)base[tid];
      float d = ws[tid];
      dinv[node] = (d > 0.f) ? rsqrtf(fmaxf(d, 1e-30f)) : 0.f;
    }
  }
  if (c == NB - 1 && tid == 0) ptr[N] = E;
  __syncthreads();
  for (int i = tid; i < m; i += 256) {
    u64 it = stage[i];
    int lo = (int)((it >> 17) & 127u);
    u32 p = atomicAdd(&cur[lo], 1u);
    sorted[b0 + (int)p] = it;
  }
}

__global__ __launch_bounds__(256) void k_pack(const u64* __restrict__ sorted,
                                              const float* __restrict__ dinv,
                                              const u32* __restrict__ H, int NBLK,
                                              u32* __restrict__ ep, int E, int NB) {
  int c = blockIdx.x;
  int b0 = (int)H[(size_t)c * NBLK];
  int b1 = (c + 1 < NB) ? (int)H[(size_t)(c + 1) * NBLK] : E;
  for (int i = b0 + threadIdx.x; i < b1; i += 256) {
    u64 it = sorted[i];
    int s = (int)(it & 0x1FFFFu);
    int dn = c * 128 + (int)((it >> 17) & 127u);
    float wv = __uint_as_float((u32)(it >> 24));
    float nv = dinv[s] * wv * dinv[dn];
    ep[i] = ((u32)f2h(nv) << 17) | (u32)s;
  }
}

// ---- R15 gather (4-edge quads, pipelined) + R20 fma_mix: ptag16 path ----
// hh = two fp16 features in one u32 (lo = feature 2f, hi = 2f+1)
__device__ __forceinline__ void acc_e2(float4& a, u32 pe, uint2 hh) {
  u32 wsh = pe >> 1;  // hi-half = fp16 weight pattern (sign-free pack)
  fmix_lo(a.x, wsh, hh.x); fmix_hi(a.y, wsh, hh.x);
  fmix_lo(a.z, wsh, hh.y); fmix_hi(a.w, wsh, hh.y);
}

template <int F4>
__device__ __forceinline__ float4 gather(const int* __restrict__ ptr, const u32* __restrict__ ep,
                                         const ushort4* __restrict__ hin, int node, int f4) {
  int e0 = ptr[node], e1 = ptr[node + 1];
  float4 a = make_float4(0.f, 0.f, 0.f, 0.f);
  int e = e0;
  while (e < e1 && (e & 3)) {
    u32 pe = ep[e];
    acc_e2(a, pe, *(const uint2*)(hin + ((u32)(pe & 0x1FFFFu) * F4 + f4)));
    ++e;
  }
  int nq = (e1 - e) >> 2;
  if (nq > 0) {
    uint4 p = *(const uint4*)(ep + e);
    uint2 h0 = *(const uint2*)(hin + ((u32)(p.x & 0x1FFFFu) * F4 + f4));
    uint2 h1 = *(const uint2*)(hin + ((u32)(p.y & 0x1FFFFu) * F4 + f4));
    uint2 h2 = *(const uint2*)(hin + ((u32)(p.z & 0x1FFFFu) * F4 + f4));
    uint2 h3 = *(const uint2*)(hin + ((u32)(p.w & 0x1FFFFu) * F4 + f4));
    for (int q = 1; q < nq; ++q) {
      uint4 pn = *(const uint4*)(ep + e + 4 * q);
      uint2 g0 = *(const uint2*)(hin + ((u32)(pn.x & 0x1FFFFu) * F4 + f4));
      uint2 g1 = *(const uint2*)(hin + ((u32)(pn.y & 0x1FFFFu) * F4 + f4));
      uint2 g2 = *(const uint2*)(hin + ((u32)(pn.z & 0x1FFFFu) * F4 + f4));
      uint2 g3 = *(const uint2*)(hin + ((u32)(pn.w & 0x1FFFFu) * F4 + f4));
      acc_e2(a, p.x, h0); acc_e2(a, p.y, h1);
      acc_e2(a, p.z, h2); acc_e2(a, p.w, h3);
      p = pn; h0 = g0; h1 = g1; h2 = g2; h3 = g3;
    }
    acc_e2(a, p.x, h0); acc_e2(a, p.y, h1);
    acc_e2(a, p.z, h2); acc_e2(a, p.w, h3);
    e += nq * 4;
  }
  while (e < e1) {
    u32 pe = ep[e];
    acc_e2(a, pe, *(const uint2*)(hin + ((u32)(pe & 0x1FFFFu) * F4 + f4)));
    ++e;
  }
  return a;
}

// ---- R21 octet gather, F=64: bank ping-pong, full-quad prefetch ----
__device__ __forceinline__ void acc8(float4& a0, float4& a1, u32 pe, uint4 r) {
  u32 wsh = pe >> 1;  // hi-half = fp16 weight
  fmix_lo(a0.x, wsh, r.x); fmix_hi(a0.y, wsh, r.x);
  fmix_lo(a0.z, wsh, r.y); fmix_hi(a0.w, wsh, r.y);
  fmix_lo(a1.x, wsh, r.z); fmix_hi(a1.y, wsh, r.z);
  fmix_lo(a1.z, wsh, r.w); fmix_hi(a1.w, wsh, r.w);
}

__device__ __forceinline__ uint4 row16(const ushort4* __restrict__ hin, u32 pe, u32 foff) {
  return *(const uint4*)(hin + ((u32)(pe & 0x1FFFFu) * 16u + foff));
}

__device__ __forceinline__ void gather64o(const int* __restrict__ ptr, const u32* __restrict__ ep,
                                          const ushort4* __restrict__ hin, int node,
                                          int f8, int o, float4& a0, float4& a1) {
  int e0 = ptr[node], e1 = ptr[node + 1];
  const u32 foff = 2u * (u32)f8;
  int e = e0;
  while (e < e1 && (e & 3)) {
    if ((e & 1) == o) {
      u32 pe = ep[e];
      acc8(a0, a1, pe, row16(hin, pe, foff));
    }
    ++e;
  }
  int nq = (e1 - e) >> 2;
  // quads for octet o: q = o + 2*j, j in [0, m)
  int m = (nq > o) ? ((nq - o + 1) >> 1) : 0;
  const u32* qb = ep + e + 4 * o;  // quad j at qb + 8*j
  if (m > 0) {
    uint4 pA = *(const uint4*)(qb);
    uint4 A0 = row16(hin, pA.x, foff), A1 = row16(hin, pA.y, foff);
    uint4 A2 = row16(hin, pA.z, foff), A3 = row16(hin, pA.w, foff);
    int j = 0;
    while (j + 2 < m) {
      // bank B prefetch (ep + 4 rows) in flight while ACC-ing bank A
      uint4 pB = *(const uint4*)(qb + 8 * (j + 1));
      uint4 B0 = row16(hin, pB.x, foff), B1 = row16(hin, pB.y, foff);
      uint4 B2 = row16(hin, pB.z, foff), B3 = row16(hin, pB.w, foff);
      acc8(a0, a1, pA.x, A0); acc8(a0, a1, pA.y, A1);
      acc8(a0, a1, pA.z, A2); acc8(a0, a1, pA.w, A3);
      // bank A prefetch (direct loads into A names: zero rotation movs)
      pA = *(const uint4*)(qb + 8 * (j + 2));
      A0 = row16(hin, pA.x, foff); A1 = row16(hin, pA.y, foff);
      A2 = row16(hin, pA.z, foff); A3 = row16(hin, pA.w, foff);
      acc8(a0, a1, pB.x, B0); acc8(a0, a1, pB.y, B1);
      acc8(a0, a1, pB.z, B2); acc8(a0, a1, pB.w, B3);
      j += 2;
    }
    if (j + 1 < m) {
      uint4 pB = *(const uint4*)(qb + 8 * (j + 1));
      uint4 B0 = row16(hin, pB.x, foff), B1 = row16(hin, pB.y, foff);
      uint4 B2 = row16(hin, pB.z, foff), B3 = row16(hin, pB.w, foff);
      acc8(a0, a1, pA.x, A0); acc8(a0, a1, pA.y, A1);
      acc8(a0, a1, pA.z, A2); acc8(a0, a1, pA.w, A3);
      acc8(a0, a1, pB.x, B0); acc8(a0, a1, pB.y, B1);
      acc8(a0, a1, pB.z, B2); acc8(a0, a1, pB.w, B3);
    } else {
      acc8(a0, a1, pA.x, A0); acc8(a0, a1, pA.y, A1);
      acc8(a0, a1, pA.z, A2); acc8(a0, a1, pA.w, A3);
    }
  }
  e += nq * 4;
  while (e < e1) {
    if ((e & 1) == o) {
      u32 pe = ep[e];
      acc8(a0, a1, pe, row16(hin, pe, foff));
    }
    ++e;
  }
}

// scalar-broadcast mm accumulate: a += t(slot ln) @ W  (R6's 28-VGPR shape).
// Tile rows are WAVE-PRIVATE (ln = tid>>4): same-wave LDS RAW needs no barrier.
__device__ __forceinline__ void mm_acc(const float* __restrict__ tl, const float4* __restrict__ Wl,
                                       int ln, int j4, float4& a) {
#pragma unroll 8
  for (int i = 0; i < 64; ++i) {
    float tv = tl[ln * 64 + ((((i >> 2) ^ ln) << 2) | (i & 3))];
    float4 wv = Wl[i * 16 + j4];
    a.x = fmaf(tv, wv.x, a.x); a.y = fmaf(tv, wv.y, a.y);
    a.z = fmaf(tv, wv.z, a.z); a.w = fmaf(tv, wv.w, a.w);
  }
}

// ---------- fused prop + matmul, F=64 (R21 octet gather) ----------
template <bool FIRST, bool LAST, bool HEAD>
__launch_bounds__(256, 8)  // guard the 64-VGPR occupancy cliff
__global__ void ptag64_k(const int* __restrict__ ptr, const u32* __restrict__ ep,
                         const ushort4* __restrict__ hin, ushort4* __restrict__ hout,
                         const float4* __restrict__ Wk4, const float4* __restrict__ W04,
                         ushort4* __restrict__ acch, const float4* __restrict__ bias4,
                         const float* __restrict__ Wout, const float* __restrict__ bout,
                         float* __restrict__ outv, int n) {
  __shared__ float4 Wl[1024];
  __shared__ float4 tl4[256];
  const float* tl = (const float*)tl4;
  int tid = threadIdx.x;
  for (int i = tid; i < 1024; i += 256) Wl[i] = Wk4[i];
  int gid = blockIdx.x * 256 + tid;
  int node = gid >> 4, j4 = gid & 15, ln = tid >> 4;
  const int o = j4 >> 3, f8 = j4 & 7;

  float4 a0 = make_float4(0.f, 0.f, 0.f, 0.f);
  float4 a1 = make_float4(0.f, 0.f, 0.f, 0.f);
  if (node < n) gather64o(ptr, ep, hin, node, f8, o, a0, a1);
  // cross-octet combine: partner lane is j4^8 within the 16-lane group
  a0.x += __shfl_xor(a0.x, 8, 16); a0.y += __shfl_xor(a0.y, 8, 16);
  a0.z += __shfl_xor(a0.z, 8, 16); a0.w += __shfl_xor(a0.w, 8, 16);
  a1.x += __shfl_xor(a1.x, 8, 16); a1.y += __shfl_xor(a1.y, 8, 16);
  a1.z += __shfl_xor(a1.z, 8, 16); a1.w += __shfl_xor(a1.w, 8, 16);
  // lane (o,f8) owns float4-group g = 2*f8+o (features 8*f8+4*o ..+4)
  float4 t = (o == 0) ? a0 : a1;
  int g = 2 * f8 + o;
  if (node < n && !LAST) hout[(size_t)node * 16 + g] = pack_h(t);
  tl4[ln * 16 + (g ^ ln)] = t;
  __syncthreads();

  float4 a = make_float4(0.f, 0.f, 0.f, 0.f);
  if (!FIRST && node < n) a = unpack_h(acch[(size_t)node * 16 + j4]);
  mm_acc(tl, Wl, ln, j4, a);
  if (FIRST) {
    __syncthreads();
    for (int i = tid; i < 1024; i += 256) Wl[i] = W04[i];
    float4 own = make_float4(0.f, 0.f, 0.f, 0.f);
    if (node < n) own = unpack_h(hin[(size_t)node * 16 + j4]);
    tl4[ln * 16 + (j4 ^ ln)] = own;
    __syncthreads();
    mm_acc(tl, Wl, ln, j4, a);
  }
  if (node >= n) return;

  if (LAST) {
    float4 b = bias4[j4];
    a.x += b.x; a.y += b.y; a.z += b.z; a.w += b.w;
    a.x = (a.x >= 0.f) ? a.x : 0.01f * a.x;
    a.y = (a.y >= 0.f) ? a.y : 0.01f * a.y;
    a.z = (a.z >= 0.f) ? a.z : 0.01f * a.z;
    a.w = (a.w >= 0.f) ? a.w : 0.01f * a.w;
    if (HEAD) {
      float v = a.x * Wout[4 * j4] + a.y * Wout[4 * j4 + 1] +
                a.z * Wout[4 * j4 + 2] + a.w * Wout[4 * j4 + 3];
      v += __shfl_down(v, 8, 16);
      v += __shfl_down(v, 4, 16);
      v += __shfl_down(v, 2, 16);
      v += __shfl_down(v, 1, 16);
      if (j4 == 0) outv[node] = v + bout[0];
    } else {
      hout[(size_t)node * 16 + j4] = pack_h(a);
    }
  } else {
    acch[(size_t)node * 16 + j4] = pack_h(a);
  }
}

// ---------- fused prop + matmul, layer 1: F_in=16 (4 lanes/node) ----------
template <bool FIRST, bool LAST>
__launch_bounds__(256)
__global__ void ptag16_k(const int* __restrict__ ptr, const u32* __restrict__ ep,
                         const ushort4* __restrict__ hin, ushort4* __restrict__ hout,
                         const float4* __restrict__ Wk4, const float4* __restrict__ W04,
                         ushort4* __restrict__ acch, const float4* __restrict__ bias4,
                         ushort4* __restrict__ outbuf, int n) {
  __shared__ float4 Wl[256];
  __shared__ float4 W0l[FIRST ? 256 : 1];
  __shared__ float4 tl4[64 * 5];
  const float* tl = (const float*)tl4;
  int tid = threadIdx.x;
  Wl[tid] = Wk4[tid];
  if (FIRST) W0l[tid] = W04[tid];
  int gid = blockIdx.x * 256 + tid;
  int node = gid >> 2, q = tid & 3, ln = tid >> 2;

  float4 t = make_float4(0.f, 0.f, 0.f, 0.f);
  if (node < n) {
    t = gather<4>(ptr, ep, hin, node, q);
    if (!LAST) hout[(size_t)node * 4 + q] = pack_h(t);
  }
  tl4[ln * 5 + q] = t;
  __syncthreads();

  float4 a[4];
#pragma unroll
  for (int c = 0; c < 4; ++c) a[c] = make_float4(0.f, 0.f, 0.f, 0.f);
  if (!FIRST && node < n) {
#pragma unroll
    for (int c = 0; c < 4; ++c) a[c] = unpack_h(acch[(size_t)node * 16 + 4 * q + c]);
  }
#pragma unroll 4
  for (int i = 0; i < 16; ++i) {
    float tv = tl[ln * 20 + i];
#pragma unroll
    for (int c = 0; c < 4; ++c) {
      float4 wv = Wl[i * 16 + 4 * q + c];
      a[c].x = fmaf(tv, wv.x, a[c].x); a[c].y = fmaf(tv, wv.y, a[c].y);
      a[c].z = fmaf(tv, wv.z, a[c].z); a[c].w = fmaf(tv, wv.w, a[c].w);
    }
  }
  if (FIRST) {
    __syncthreads();
    float4 own = make_float4(0.f, 0.f, 0.f, 0.f);
    if (node < n) own = unpack_h(hin[(size_t)node * 4 + q]);
    tl4[ln * 5 + q] = own;
    __syncthreads();
#pragma unroll 4
    for (int i = 0; i < 16; ++i) {
      float tv = tl[ln * 20 + i];
#pragma unroll
      for (int c = 0; c < 4; ++c) {
        float4 wv = W0l[i * 16 + 4 * q + c];
        a[c].x = fmaf(tv, wv.x, a[c].x); a[c].y = fmaf(tv, wv.y, a[c].y);
        a[c].z = fmaf(tv, wv.z, a[c].z); a[c].w = fmaf(tv, wv.w, a[c].w);
      }
    }
  }
  if (node >= n) return;

  if (LAST) {
#pragma unroll
    for (int c = 0; c < 4; ++c) {
      float4 b = bias4[4 * q + c];
      a[c].x += b.x; a[c].y += b.y; a[c].z += b.z; a[c].w += b.w;
      a[c].x = (a[c].x >= 0.f) ? a[c].x : 0.01f * a[c].x;
      a[c].y = (a[c].y >= 0.f) ? a[c].y : 0.01f * a[c].y;
      a[c].z = (a[c].z >= 0.f) ? a[c].z : 0.01f * a[c].z;
      a[c].w = (a[c].w >= 0.f) ? a[c].w : 0.01f * a[c].w;
      outbuf[(size_t)node * 16 + 4 * q + c] = pack_h(a[c]);
    }
  } else {
#pragma unroll
    for (int c = 0; c < 4; ++c) acch[(size_t)node * 16 + 4 * q + c] = pack_h(a[c]);
  }
}

extern "C" void kernel_launch(void* const* d_in, const int* in_sizes, int n_in,
                              void* d_out, int out_size, void* d_ws, size_t ws_size,
                              hipStream_t stream) {
  const float* x    = (const float*)d_in[0];
  const int*   ei   = (const int*)d_in[1];
  const float* ew   = (const float*)d_in[2];
  const float* W1   = (const float*)d_in[4];
  const float* b1   = (const float*)d_in[5];
  const float* W2   = (const float*)d_in[6];
  const float* b2   = (const float*)d_in[7];
  const float* Wout = (const float*)d_in[8];
  const float* bout = (const float*)d_in[9];
  float* out = (float*)d_out;

  const int N = in_sizes[0] / 16;
  const int E = in_sizes[2];
  const int* src = ei;
  const int* dst = ei + E;

  const int NBLK = 256;
  const int CH = (E + NBLK - 1) / NBLK;
  const int NB = (N + 127) >> 7;
  const int HN = NB * NBLK;

  char* ws = (char*)d_ws;
  size_t off = 0;
  auto alloc = [&](size_t bytes) {
    char* p = ws + off;
    off = (off + bytes + 255) & ~(size_t)255;
    return p;
  };
  u32*     H      = (u32*)alloc((size_t)HN * 4);
  u32*     bsum   = (u32*)alloc(4096);
  float*   dinv   = (float*)alloc((size_t)N * 4);
  int*     ptr    = (int*)alloc(((size_t)N + 1) * 4);
  u64*     sorted = (u64*)alloc((size_t)E * 8);
  u32*     ep     = (u32*)alloc((size_t)E * 4);
  ushort4* xh     = (ushort4*)alloc((size_t)N * 16 * 2);
  ushort4* hb0    = (ushort4*)alloc((size_t)N * 64 * 2);
  ushort4* hb1    = (ushort4*)alloc((size_t)N * 64 * 2);
  ushort4* hb2    = (ushort4*)alloc((size_t)N * 64 * 2);
  ushort4* acch   = (ushort4*)alloc((size_t)N * 64 * 2);

  // ---- atomic-free CSR build ----
  k_hist<<<NBLK, 256, 0, stream>>>(dst, H, E, CH, NB, (const float4*)x, xh, N * 4);
  scanH_blocks<<<HN / 256, 256, 0, stream>>>(H, bsum, HN);
  scanH_sums<<<1, 1024, 0, stream>>>(bsum, HN / 256);
  scanH_add<<<HN / 256, 256, 0, stream>>>(H, bsum, HN);
  k_scatter<<<NBLK, 256, 0, stream>>>(src, dst, ew, H, sorted, E, CH, NB);
  k_bucket<<<NB, 256, 0, stream>>>(sorted, H, NBLK, ptr, dinv, N, E, NB);
  k_pack<<<NB, 256, 0, stream>>>(sorted, dinv, H, NBLK, ep, E, NB);

  int g4  = (N * 4 + 255) / 256;   // layer-1 fused (4 lanes/node)
  int g16 = (N * 16 + 255) / 256;  // F=64 fused

  auto W1k = [&](int k) { return (const float4*)(W1 + (size_t)k * 1024); };
  auto W2k = [&](int l, int k) { return (const float4*)(W2 + ((size_t)l * 5 + k) * 4096); };

  // ---- Layer 1 (16 -> 64): acc in acch, t ping-pong hb0/hb1, h1 -> hb2 ----
  ptag16_k<true,  false><<<g4, 256, 0, stream>>>(ptr, ep, xh,  hb0, W1k(1), W1k(0), acch, nullptr, nullptr, N);
  ptag16_k<false, false><<<g4, 256, 0, stream>>>(ptr, ep, hb0, hb1, W1k(2), nullptr, acch, nullptr, nullptr, N);
  ptag16_k<false, false><<<g4, 256, 0, stream>>>(ptr, ep, hb1, hb0, W1k(3), nullptr, acch, nullptr, nullptr, N);
  ptag16_k<false, true ><<<g4, 256, 0, stream>>>(ptr, ep, hb0, nullptr, W1k(4), nullptr, acch,
                                                 (const float4*)b1, hb2, N);

  // ---- Layers 2+3 + head: R21 fused kernels (20KiB LDS, <=64 VGPR) ----
  ptag64_k<true,  false, false><<<g16, 256, 0, stream>>>(ptr, ep, hb2, hb0, W2k(0,1), W2k(0,0), acch,
                                                         nullptr, nullptr, nullptr, nullptr, N);
  ptag64_k<false, false, false><<<g16, 256, 0, stream>>>(ptr, ep, hb0, hb1, W2k(0,2), nullptr, acch,
                                                         nullptr, nullptr, nullptr, nullptr, N);
  ptag64_k<false, false, false><<<g16, 256, 0, stream>>>(ptr, ep, hb1, hb0, W2k(0,3), nullptr, acch,
                                                         nullptr, nullptr, nullptr, nullptr, N);
  ptag64_k<false, true,  false><<<g16, 256, 0, stream>>>(ptr, ep, hb0, hb2, W2k(0,4), nullptr, acch,
                                                         (const float4*)b2, nullptr, nullptr, nullptr, N);
  ptag64_k<true,  false, false><<<g16, 256, 0, stream>>>(ptr, ep, hb2, hb0, W2k(1,1), W2k(1,0), acch,
                                                         nullptr, nullptr, nullptr, nullptr, N);
  ptag64_k<false, false, false><<<g16, 256, 0, stream>>>(ptr, ep, hb0, hb1, W2k(1,2), nullptr, acch,
                                                         nullptr, nullptr, nullptr, nullptr, N);
  ptag64_k<false, false, false><<<g16, 256, 0, stream>>>(ptr, ep, hb1, hb0, W2k(1,3), nullptr, acch,
                                                         nullptr, nullptr, nullptr, nullptr, N);
  ptag64_k<false, true,  true ><<<g16, 256, 0, stream>>>(ptr, ep, hb0, nullptr, W2k(1,4), nullptr, acch,
                                                         (const float4*)(b2 + 64), Wout, bout, out, N);
}

// Round 10
// 921.968 us; speedup vs baseline: 1.0616x; 1.0204x over previous
//
#include <hip/hip_runtime.h>

// ---------------------------------------------------------------------------
// TAGCN node regression: 3 TAGConv layers (K=4) + linear head, fp32 math.
// R14: zero-global-atomic CSR build (two-level bucket sort).
// R15/R16/R20/R21: gather ladder 102->82us (quad pipeline, octet split,
// v_fma_mix, bank ping-pong). ptag64 now ~= L2-miss-path roofline:
// 161MB L2-miss @ ~2.3TB/s ~= 70us of 82us dur; random graph -> no src
// locality left. 20KiB LDS / <=64 VGPR are proven occupancy cliffs.
// R18/R19 NULL: degree divergence was not a cost.
// R22: k_scatter was 83us at 9.6% occupancy (256 blocks = 1/CU; latency-
// bound scattered 8B writes, WRITE 85.8MB sector waste). Cursor scheme is
// grid-agnostic -> NBH=1024 blocks (4/CU) for k_hist/k_scatter; scanH_sums
// rewritten as looped scan w/ carry (nb=3128); bsum alloc 4KB->16KB.
// ---------------------------------------------------------------------------

typedef unsigned long long u64;
typedef unsigned int u32;

__device__ __forceinline__ float h2f(unsigned short u) {
  _Float16 h;
  __builtin_memcpy(&h, &u, 2);
  return (float)h;
}
__device__ __forceinline__ unsigned short f2h(float f) {
  _Float16 h = (_Float16)f;  // RNE
  unsigned short u;
  __builtin_memcpy(&u, &h, 2);
  return u;
}
__device__ __forceinline__ ushort4 pack_h(float4 v) {
  ushort4 r;
  r.x = f2h(v.x); r.y = f2h(v.y); r.z = f2h(v.z); r.w = f2h(v.w);
  return r;
}
__device__ __forceinline__ float4 unpack_h(ushort4 u) {
  return make_float4(h2f(u.x), h2f(u.y), h2f(u.z), h2f(u.w));
}

// fma_mix helpers: acc += f16(hi of wsh) * f16(lo/hi of h)   [fp32 FMA]
__device__ __forceinline__ void fmix_lo(float& acc, u32 wsh, u32 h) {
  asm("v_fma_mix_f32 %0, %1, %2, %0 op_sel:[1,0,0] op_sel_hi:[1,1,0]"
      : "+v"(acc) : "v"(wsh), "v"(h));
}
__device__ __forceinline__ void fmix_hi(float& acc, u32 wsh, u32 h) {
  asm("v_fma_mix_f32 %0, %1, %2, %0 op_sel:[1,1,0] op_sel_hi:[1,1,0]"
      : "+v"(acc) : "v"(wsh), "v"(h));
}

// ---------------- atomic-free CSR build ----------------
// coarse bucket = dst >> 7 (128 nodes/bucket). NB <= 1024 (N <= 131072).
// item u64 = [0:8][w_f32:32][dst_low7:7][src:17]

__global__ __launch_bounds__(256) void k_hist(const int* __restrict__ dst, u32* __restrict__ H,
                                              int E, int CH, int NB,
                                              const float4* __restrict__ x4,
                                              ushort4* __restrict__ xh, int n4) {
  __shared__ u32 hc[1024];
  int tid = threadIdx.x, blk = blockIdx.x, nblk = gridDim.x;
  for (int i = tid; i < 1024; i += 256) hc[i] = 0;
  for (int i = blk * 256 + tid; i < n4; i += nblk * 256) xh[i] = pack_h(x4[i]);
  __syncthreads();
  int e0 = blk * CH, e1 = min(E, e0 + CH);
  for (int e = e0 + tid; e < e1; e += 256) atomicAdd(&hc[((u32)dst[e]) >> 7], 1u);
  __syncthreads();
  for (int c = tid; c < NB; c += 256) H[(size_t)c * nblk + blk] = hc[c];
}

__global__ void scanH_blocks(u32* __restrict__ H, u32* __restrict__ bsum, int n) {
  __shared__ u32 s[256];
  int tid = threadIdx.x;
  int i = blockIdx.x * 256 + tid;
  u32 v = (i < n) ? H[i] : 0;
  s[tid] = v;
  __syncthreads();
#pragma unroll
  for (int off = 1; off < 256; off <<= 1) {
    u32 t = (tid >= off) ? s[tid - off] : 0;
    __syncthreads();
    s[tid] += t;
    __syncthreads();
  }
  if (i < n) H[i] = s[tid] - v;
  if (tid == 255) bsum[blockIdx.x] = s[255];
}

// looped exclusive scan with carry: supports any nb (R22)
__global__ void scanH_sums(u32* __restrict__ bsum, int nb) {
  __shared__ u32 s[1024];
  __shared__ u32 carry;
  int tid = threadIdx.x;
  if (tid == 0) carry = 0;
  __syncthreads();
  for (int base = 0; base < nb; base += 1024) {
    int i = base + tid;
    u32 v = (i < nb) ? bsum[i] : 0;
    s[tid] = v;
    __syncthreads();
#pragma unroll
    for (int off = 1; off < 1024; off <<= 1) {
      u32 t = (tid >= off) ? s[tid - off] : 0;
      __syncthreads();
      s[tid] += t;
      __syncthreads();
    }
    u32 c = carry;
    if (i < nb) bsum[i] = s[tid] - v + c;
    __syncthreads();
    if (tid == 1023) carry = c + s[1023];
    __syncthreads();
  }
}

__global__ void scanH_add(u32* __restrict__ H, const u32* __restrict__ bsum, int n) {
  int i = blockIdx.x * blockDim.x + threadIdx.x;
  if (i < n) H[i] += bsum[i >> 8];
}

__global__ __launch_bounds__(256) void k_scatter(const int* __restrict__ src,
                                                 const int* __restrict__ dst,
                                                 const float* __restrict__ w,
                                                 const u32* __restrict__ H,
                                                 u64* __restrict__ sorted, int E, int CH, int NB) {
  __shared__ u32 cur[1024];
  int tid = threadIdx.x, blk = blockIdx.x, nblk = gridDim.x;
  for (int c = tid; c < NB; c += 256) cur[c] = H[(size_t)c * nblk + blk];
  __syncthreads();
  int e0 = blk * CH, e1 = min(E, e0 + CH);
  for (int e = e0 + tid; e < e1; e += 256) {
    int d = dst[e];
    int c = ((u32)d) >> 7;
    u32 p = atomicAdd(&cur[c], 1u);
    u64 it = (u64)(u32)src[e] | ((u64)((u32)d & 127u) << 17) |
             ((u64)__float_as_uint(w[e]) << 24);
    sorted[p] = it;
  }
}

#define BCAP 6144
__global__ __launch_bounds__(256) void k_bucket(u64* __restrict__ sorted,
                                                const u32* __restrict__ H, int NBLK,
                                                int* __restrict__ ptr, float* __restrict__ dinv,
                                                int N, int E, int NB) {
  __shared__ u64 stage[BCAP];
  __shared__ u32 cnt[128], base[128], cur[128], tmp[128];
  __shared__ float ws[128];
  int c = blockIdx.x, tid = threadIdx.x;
  int b0 = (int)H[(size_t)c * NBLK];
  int b1 = (c + 1 < NB) ? (int)H[(size_t)(c + 1) * NBLK] : E;
  int m = b1 - b0;
  if (tid < 128) { cnt[tid] = 0; ws[tid] = 0.f; }
  __syncthreads();
  for (int i = tid; i < m; i += 256) {
    u64 it = sorted[b0 + i];
    stage[i] = it;
    int lo = (int)((it >> 17) & 127u);
    atomicAdd(&cnt[lo], 1u);
    atomicAdd(&ws[lo], __uint_as_float((u32)(it >> 24)));
  }
  __syncthreads();
  u32 v = (tid < 128) ? cnt[tid] : 0;
  if (tid < 128) tmp[tid] = v;
  __syncthreads();
#pragma unroll
  for (int off = 1; off < 128; off <<= 1) {
    u32 t = 0;
    if (tid < 128 && tid >= off) t = tmp[tid - off];
    __syncthreads();
    if (tid < 128) tmp[tid] += t;
    __syncthreads();
  }
  if (tid < 128) {
    base[tid] = tmp[tid] - v;
    cur[tid] = tmp[tid] - v;
    int node = c * 128 + tid;
    if (node < N) {
      ptr[node] = b0 + (int)base[tid];
      float d = ws[tid];
      dinv[node] = (d > 0.f) ? rsqrtf(fmaxf(d, 1e-30f)) : 0.f;
    }
  }
  if (c == NB - 1 && tid == 0) ptr[N] = E;
  __syncthreads();
  for (int i = tid; i < m; i += 256) {
    u64 it = stage[i];
    int lo = (int)((it >> 17) & 127u);
    u32 p = atomicAdd(&cur[lo], 1u);
    sorted[b0 + (int)p] = it;
  }
}

__global__ __launch_bounds__(256) void k_pack(const u64* __restrict__ sorted,
                                              const float* __restrict__ dinv,
                                              const u32* __restrict__ H, int NBLK,
                                              u32* __restrict__ ep, int E, int NB) {
  int c = blockIdx.x;
  int b0 = (int)H[(size_t)c * NBLK];
  int b1 = (c + 1 < NB) ? (int)H[(size_t)(c + 1) * NBLK] : E;
  for (int i = b0 + threadIdx.x; i < b1; i += 256) {
    u64 it = sorted[i];
    int s = (int)(it & 0x1FFFFu);
    int dn = c * 128 + (int)((it >> 17) & 127u);
    float wv = __uint_as_float((u32)(it >> 24));
    float nv = dinv[s] * wv * dinv[dn];
    ep[i] = ((u32)f2h(nv) << 17) | (u32)s;
  }
}

// ---- R15 gather (4-edge quads, pipelined) + R20 fma_mix: ptag16 path ----
// hh = two fp16 features in one u32 (lo = feature 2f, hi = 2f+1)
__device__ __forceinline__ void acc_e2(float4& a, u32 pe, uint2 hh) {
  u32 wsh = pe >> 1;  // hi-half = fp16 weight pattern (sign-free pack)
  fmix_lo(a.x, wsh, hh.x); fmix_hi(a.y, wsh, hh.x);
  fmix_lo(a.z, wsh, hh.y); fmix_hi(a.w, wsh, hh.y);
}

template <int F4>
__device__ __forceinline__ float4 gather(const int* __restrict__ ptr, const u32* __restrict__ ep,
                                         const ushort4* __restrict__ hin, int node, int f4) {
  int e0 = ptr[node], e1 = ptr[node + 1];
  float4 a = make_float4(0.f, 0.f, 0.f, 0.f);
  int e = e0;
  while (e < e1 && (e & 3)) {
    u32 pe = ep[e];
    acc_e2(a, pe, *(const uint2*)(hin + ((u32)(pe & 0x1FFFFu) * F4 + f4)));
    ++e;
  }
  int nq = (e1 - e) >> 2;
  if (nq > 0) {
    uint4 p = *(const uint4*)(ep + e);
    uint2 h0 = *(const uint2*)(hin + ((u32)(p.x & 0x1FFFFu) * F4 + f4));
    uint2 h1 = *(const uint2*)(hin + ((u32)(p.y & 0x1FFFFu) * F4 + f4));
    uint2 h2 = *(const uint2*)(hin + ((u32)(p.z & 0x1FFFFu) * F4 + f4));
    uint2 h3 = *(const uint2*)(hin + ((u32)(p.w & 0x1FFFFu) * F4 + f4));
    for (int q = 1; q < nq; ++q) {
      uint4 pn = *(const uint4*)(ep + e + 4 * q);
      uint2 g0 = *(const uint2*)(hin + ((u32)(pn.x & 0x1FFFFu) * F4 + f4));
      uint2 g1 = *(const uint2*)(hin + ((u32)(pn.y & 0x1FFFFu) * F4 + f4));
      uint2 g2 = *(const uint2*)(hin + ((u32)(pn.z & 0x1FFFFu) * F4 + f4));
      uint2 g3 = *(const uint2*)(hin + ((u32)(pn.w & 0x1FFFFu) * F4 + f4));
      acc_e2(a, p.x, h0); acc_e2(a, p.y, h1);
      acc_e2(a, p.z, h2); acc_e2(a, p.w, h3);
      p = pn; h0 = g0; h1 = g1; h2 = g2; h3 = g3;
    }
    acc_e2(a, p.x, h0); acc_e2(a, p.y, h1);
    acc_e2(a, p.z, h2); acc_e2(a, p.w, h3);
    e += nq * 4;
  }
  while (e < e1) {
    u32 pe = ep[e];
    acc_e2(a, pe, *(const uint2*)(hin + ((u32)(pe & 0x1FFFFu) * F4 + f4)));
    ++e;
  }
  return a;
}

// ---- R21 octet gather, F=64: bank ping-pong, full-quad prefetch ----
__device__ __forceinline__ void acc8(float4& a0, float4& a1, u32 pe, uint4 r) {
  u32 wsh = pe >> 1;  // hi-half = fp16 weight
  fmix_lo(a0.x, wsh, r.x); fmix_hi(a0.y, wsh, r.x);
  fmix_lo(a0.z, wsh, r.y); fmix_hi(a0.w, wsh, r.y);
  fmix_lo(a1.x, wsh, r.z); fmix_hi(a1.y, wsh, r.z);
  fmix_lo(a1.z, wsh, r.w); fmix_hi(a1.w, wsh, r.w);
}

__device__ __forceinline__ uint4 row16(const ushort4* __restrict__ hin, u32 pe, u32 foff) {
  return *(const uint4*)(hin + ((u32)(pe & 0x1FFFFu) * 16u + foff));
}

__device__ __forceinline__ void gather64o(const int* __restrict__ ptr, const u32* __restrict__ ep,
                                          const ushort4* __restrict__ hin, int node,
                                          int f8, int o, float4& a0, float4& a1) {
  int e0 = ptr[node], e1 = ptr[node + 1];
  const u32 foff = 2u * (u32)f8;
  int e = e0;
  while (e < e1 && (e & 3)) {
    if ((e & 1) == o) {
      u32 pe = ep[e];
      acc8(a0, a1, pe, row16(hin, pe, foff));
    }
    ++e;
  }
  int nq = (e1 - e) >> 2;
  // quads for octet o: q = o + 2*j, j in [0, m)
  int m = (nq > o) ? ((nq - o + 1) >> 1) : 0;
  const u32* qb = ep + e + 4 * o;  // quad j at qb + 8*j
  if (m > 0) {
    uint4 pA = *(const uint4*)(qb);
    uint4 A0 = row16(hin, pA.x, foff), A1 = row16(hin, pA.y, foff);
    uint4 A2 = row16(hin, pA.z, foff), A3 = row16(hin, pA.w, foff);
    int j = 0;
    while (j + 2 < m) {
      uint4 pB = *(const uint4*)(qb + 8 * (j + 1));
      uint4 B0 = row16(hin, pB.x, foff), B1 = row16(hin, pB.y, foff);
      uint4 B2 = row16(hin, pB.z, foff), B3 = row16(hin, pB.w, foff);
      acc8(a0, a1, pA.x, A0); acc8(a0, a1, pA.y, A1);
      acc8(a0, a1, pA.z, A2); acc8(a0, a1, pA.w, A3);
      pA = *(const uint4*)(qb + 8 * (j + 2));
      A0 = row16(hin, pA.x, foff); A1 = row16(hin, pA.y, foff);
      A2 = row16(hin, pA.z, foff); A3 = row16(hin, pA.w, foff);
      acc8(a0, a1, pB.x, B0); acc8(a0, a1, pB.y, B1);
      acc8(a0, a1, pB.z, B2); acc8(a0, a1, pB.w, B3);
      j += 2;
    }
    if (j + 1 < m) {
      uint4 pB = *(const uint4*)(qb + 8 * (j + 1));
      uint4 B0 = row16(hin, pB.x, foff), B1 = row16(hin, pB.y, foff);
      uint4 B2 = row16(hin, pB.z, foff), B3 = row16(hin, pB.w, foff);
      acc8(a0, a1, pA.x, A0); acc8(a0, a1, pA.y, A1);
      acc8(a0, a1, pA.z, A2); acc8(a0, a1, pA.w, A3);
      acc8(a0, a1, pB.x, B0); acc8(a0, a1, pB.y, B1);
      acc8(a0, a1, pB.z, B2); acc8(a0, a1, pB.w, B3);
    } else {
      acc8(a0, a1, pA.x, A0); acc8(a0, a1, pA.y, A1);
      acc8(a0, a1, pA.z, A2); acc8(a0, a1, pA.w, A3);
    }
  }
  e += nq * 4;
  while (e < e1) {
    if ((e & 1) == o) {
      u32 pe = ep[e];
      acc8(a0, a1, pe, row16(hin, pe, foff));
    }
    ++e;
  }
}

// scalar-broadcast mm accumulate: a += t(slot ln) @ W  (R6's 28-VGPR shape).
// Tile rows are WAVE-PRIVATE (ln = tid>>4): same-wave LDS RAW needs no barrier.
__device__ __forceinline__ void mm_acc(const float* __restrict__ tl, const float4* __restrict__ Wl,
                                       int ln, int j4, float4& a) {
#pragma unroll 8
  for (int i = 0; i < 64; ++i) {
    float tv = tl[ln * 64 + ((((i >> 2) ^ ln) << 2) | (i & 3))];
    float4 wv = Wl[i * 16 + j4];
    a.x = fmaf(tv, wv.x, a.x); a.y = fmaf(tv, wv.y, a.y);
    a.z = fmaf(tv, wv.z, a.z); a.w = fmaf(tv, wv.w, a.w);
  }
}

// ---------- fused prop + matmul, F=64 (R21 octet gather) ----------
template <bool FIRST, bool LAST, bool HEAD>
__launch_bounds__(256, 8)  // guard the 64-VGPR occupancy cliff
__global__ void ptag64_k(const int* __restrict__ ptr, const u32* __restrict__ ep,
                         const ushort4* __restrict__ hin, ushort4* __restrict__ hout,
                         const float4* __restrict__ Wk4, const float4* __restrict__ W04,
                         ushort4* __restrict__ acch, const float4* __restrict__ bias4,
                         const float* __restrict__ Wout, const float* __restrict__ bout,
                         float* __restrict__ outv, int n) {
  __shared__ float4 Wl[1024];
  __shared__ float4 tl4[256];
  const float* tl = (const float*)tl4;
  int tid = threadIdx.x;
  for (int i = tid; i < 1024; i += 256) Wl[i] = Wk4[i];
  int gid = blockIdx.x * 256 + tid;
  int node = gid >> 4, j4 = gid & 15, ln = tid >> 4;
  const int o = j4 >> 3, f8 = j4 & 7;

  float4 a0 = make_float4(0.f, 0.f, 0.f, 0.f);
  float4 a1 = make_float4(0.f, 0.f, 0.f, 0.f);
  if (node < n) gather64o(ptr, ep, hin, node, f8, o, a0, a1);
  // cross-octet combine: partner lane is j4^8 within the 16-lane group
  a0.x += __shfl_xor(a0.x, 8, 16); a0.y += __shfl_xor(a0.y, 8, 16);
  a0.z += __shfl_xor(a0.z, 8, 16); a0.w += __shfl_xor(a0.w, 8, 16);
  a1.x += __shfl_xor(a1.x, 8, 16); a1.y += __shfl_xor(a1.y, 8, 16);
  a1.z += __shfl_xor(a1.z, 8, 16); a1.w += __shfl_xor(a1.w, 8, 16);
  // lane (o,f8) owns float4-group g = 2*f8+o (features 8*f8+4*o ..+4)
  float4 t = (o == 0) ? a0 : a1;
  int g = 2 * f8 + o;
  if (node < n && !LAST) hout[(size_t)node * 16 + g] = pack_h(t);
  tl4[ln * 16 + (g ^ ln)] = t;
  __syncthreads();

  float4 a = make_float4(0.f, 0.f, 0.f, 0.f);
  if (!FIRST && node < n) a = unpack_h(acch[(size_t)node * 16 + j4]);
  mm_acc(tl, Wl, ln, j4, a);
  if (FIRST) {
    __syncthreads();
    for (int i = tid; i < 1024; i += 256) Wl[i] = W04[i];
    float4 own = make_float4(0.f, 0.f, 0.f, 0.f);
    if (node < n) own = unpack_h(hin[(size_t)node * 16 + j4]);
    tl4[ln * 16 + (j4 ^ ln)] = own;
    __syncthreads();
    mm_acc(tl, Wl, ln, j4, a);
  }
  if (node >= n) return;

  if (LAST) {
    float4 b = bias4[j4];
    a.x += b.x; a.y += b.y; a.z += b.z; a.w += b.w;
    a.x = (a.x >= 0.f) ? a.x : 0.01f * a.x;
    a.y = (a.y >= 0.f) ? a.y : 0.01f * a.y;
    a.z = (a.z >= 0.f) ? a.z : 0.01f * a.z;
    a.w = (a.w >= 0.f) ? a.w : 0.01f * a.w;
    if (HEAD) {
      float v = a.x * Wout[4 * j4] + a.y * Wout[4 * j4 + 1] +
                a.z * Wout[4 * j4 + 2] + a.w * Wout[4 * j4 + 3];
      v += __shfl_down(v, 8, 16);
      v += __shfl_down(v, 4, 16);
      v += __shfl_down(v, 2, 16);
      v += __shfl_down(v, 1, 16);
      if (j4 == 0) outv[node] = v + bout[0];
    } else {
      hout[(size_t)node * 16 + j4] = pack_h(a);
    }
  } else {
    acch[(size_t)node * 16 + j4] = pack_h(a);
  }
}

// ---------- fused prop + matmul, layer 1: F_in=16 (4 lanes/node) ----------
template <bool FIRST, bool LAST>
__launch_bounds__(256)
__global__ void ptag16_k(const int* __restrict__ ptr, const u32* __restrict__ ep,
                         const ushort4* __restrict__ hin, ushort4* __restrict__ hout,
                         const float4* __restrict__ Wk4, const float4* __restrict__ W04,
                         ushort4* __restrict__ acch, const float4* __restrict__ bias4,
                         ushort4* __restrict__ outbuf, int n) {
  __shared__ float4 Wl[256];
  __shared__ float4 W0l[FIRST ? 256 : 1];
  __shared__ float4 tl4[64 * 5];
  const float* tl = (const float*)tl4;
  int tid = threadIdx.x;
  Wl[tid] = Wk4[tid];
  if (FIRST) W0l[tid] = W04[tid];
  int gid = blockIdx.x * 256 + tid;
  int node = gid >> 2, q = tid & 3, ln = tid >> 2;

  float4 t = make_float4(0.f, 0.f, 0.f, 0.f);
  if (node < n) {
    t = gather<4>(ptr, ep, hin, node, q);
    if (!LAST) hout[(size_t)node * 4 + q] = pack_h(t);
  }
  tl4[ln * 5 + q] = t;
  __syncthreads();

  float4 a[4];
#pragma unroll
  for (int c = 0; c < 4; ++c) a[c] = make_float4(0.f, 0.f, 0.f, 0.f);
  if (!FIRST && node < n) {
#pragma unroll
    for (int c = 0; c < 4; ++c) a[c] = unpack_h(acch[(size_t)node * 16 + 4 * q + c]);
  }
#pragma unroll 4
  for (int i = 0; i < 16; ++i) {
    float tv = tl[ln * 20 + i];
#pragma unroll
    for (int c = 0; c < 4; ++c) {
      float4 wv = Wl[i * 16 + 4 * q + c];
      a[c].x = fmaf(tv, wv.x, a[c].x); a[c].y = fmaf(tv, wv.y, a[c].y);
      a[c].z = fmaf(tv, wv.z, a[c].z); a[c].w = fmaf(tv, wv.w, a[c].w);
    }
  }
  if (FIRST) {
    __syncthreads();
    float4 own = make_float4(0.f, 0.f, 0.f, 0.f);
    if (node < n) own = unpack_h(hin[(size_t)node * 4 + q]);
    tl4[ln * 5 + q] = own;
    __syncthreads();
#pragma unroll 4
    for (int i = 0; i < 16; ++i) {
      float tv = tl[ln * 20 + i];
#pragma unroll
      for (int c = 0; c < 4; ++c) {
        float4 wv = W0l[i * 16 + 4 * q + c];
        a[c].x = fmaf(tv, wv.x, a[c].x); a[c].y = fmaf(tv, wv.y, a[c].y);
        a[c].z = fmaf(tv, wv.z, a[c].z); a[c].w = fmaf(tv, wv.w, a[c].w);
      }
    }
  }
  if (node >= n) return;

  if (LAST) {
#pragma unroll
    for (int c = 0; c < 4; ++c) {
      float4 b = bias4[4 * q + c];
      a[c].x += b.x; a[c].y += b.y; a[c].z += b.z; a[c].w += b.w;
      a[c].x = (a[c].x >= 0.f) ? a[c].x : 0.01f * a[c].x;
      a[c].y = (a[c].y >= 0.f) ? a[c].y : 0.01f * a[c].y;
      a[c].z = (a[c].z >= 0.f) ? a[c].z : 0.01f * a[c].z;
      a[c].w = (a[c].w >= 0.f) ? a[c].w : 0.01f * a[c].w;
      outbuf[(size_t)node * 16 + 4 * q + c] = pack_h(a[c]);
    }
  } else {
#pragma unroll
    for (int c = 0; c < 4; ++c) acch[(size_t)node * 16 + 4 * q + c] = pack_h(a[c]);
  }
}

extern "C" void kernel_launch(void* const* d_in, const int* in_sizes, int n_in,
                              void* d_out, int out_size, void* d_ws, size_t ws_size,
                              hipStream_t stream) {
  const float* x    = (const float*)d_in[0];
  const int*   ei   = (const int*)d_in[1];
  const float* ew   = (const float*)d_in[2];
  const float* W1   = (const float*)d_in[4];
  const float* b1   = (const float*)d_in[5];
  const float* W2   = (const float*)d_in[6];
  const float* b2   = (const float*)d_in[7];
  const float* Wout = (const float*)d_in[8];
  const float* bout = (const float*)d_in[9];
  float* out = (float*)d_out;

  const int N = in_sizes[0] / 16;
  const int E = in_sizes[2];
  const int* src = ei;
  const int* dst = ei + E;

  const int NBH = 1024;                      // hist/scatter blocks (R22: 4/CU)
  const int CH = (E + NBH - 1) / NBH;        // edges per block
  const int NB = (N + 127) >> 7;             // coarse buckets (<=1024)
  const int HN = NB * NBH;                   // hist entries (multiple of 256)

  char* ws = (char*)d_ws;
  size_t off = 0;
  auto alloc = [&](size_t bytes) {
    char* p = ws + off;
    off = (off + bytes + 255) & ~(size_t)255;
    return p;
  };
  u32*     H      = (u32*)alloc((size_t)HN * 4);
  u32*     bsum   = (u32*)alloc(16384);      // HN/256 entries (R22: 4KB->16KB)
  float*   dinv   = (float*)alloc((size_t)N * 4);
  int*     ptr    = (int*)alloc(((size_t)N + 1) * 4);
  u64*     sorted = (u64*)alloc((size_t)E * 8);
  u32*     ep     = (u32*)alloc((size_t)E * 4);
  ushort4* xh     = (ushort4*)alloc((size_t)N * 16 * 2);
  ushort4* hb0    = (ushort4*)alloc((size_t)N * 64 * 2);
  ushort4* hb1    = (ushort4*)alloc((size_t)N * 64 * 2);
  ushort4* hb2    = (ushort4*)alloc((size_t)N * 64 * 2);
  ushort4* acch   = (ushort4*)alloc((size_t)N * 64 * 2);

  // ---- atomic-free CSR build ----
  k_hist<<<NBH, 256, 0, stream>>>(dst, H, E, CH, NB, (const float4*)x, xh, N * 4);
  scanH_blocks<<<HN / 256, 256, 0, stream>>>(H, bsum, HN);
  scanH_sums<<<1, 1024, 0, stream>>>(bsum, HN / 256);
  scanH_add<<<HN / 256, 256, 0, stream>>>(H, bsum, HN);
  k_scatter<<<NBH, 256, 0, stream>>>(src, dst, ew, H, sorted, E, CH, NB);
  k_bucket<<<NB, 256, 0, stream>>>(sorted, H, NBH, ptr, dinv, N, E, NB);
  k_pack<<<NB, 256, 0, stream>>>(sorted, dinv, H, NBH, ep, E, NB);

  int g4  = (N * 4 + 255) / 256;   // layer-1 fused (4 lanes/node)
  int g16 = (N * 16 + 255) / 256;  // F=64 fused

  auto W1k = [&](int k) { return (const float4*)(W1 + (size_t)k * 1024); };
  auto W2k = [&](int l, int k) { return (const float4*)(W2 + ((size_t)l * 5 + k) * 4096); };

  // ---- Layer 1 (16 -> 64): acc in acch, t ping-pong hb0/hb1, h1 -> hb2 ----
  ptag16_k<true,  false><<<g4, 256, 0, stream>>>(ptr, ep, xh,  hb0, W1k(1), W1k(0), acch, nullptr, nullptr, N);
  ptag16_k<false, false><<<g4, 256, 0, stream>>>(ptr, ep, hb0, hb1, W1k(2), nullptr, acch, nullptr, nullptr, N);
  ptag16_k<false, false><<<g4, 256, 0, stream>>>(ptr, ep, hb1, hb0, W1k(3), nullptr, acch, nullptr, nullptr, N);
  ptag16_k<false, true ><<<g4, 256, 0, stream>>>(ptr, ep, hb0, nullptr, W1k(4), nullptr, acch,
                                                 (const float4*)b1, hb2, N);

  // ---- Layers 2+3 + head: R21 fused kernels (20KiB LDS, <=64 VGPR) ----
  ptag64_k<true,  false, false><<<g16, 256, 0, stream>>>(ptr, ep, hb2, hb0, W2k(0,1), W2k(0,0), acch,
                                                         nullptr, nullptr, nullptr, nullptr, N);
  ptag64_k<false, false, false><<<g16, 256, 0, stream>>>(ptr, ep, hb0, hb1, W2k(0,2), nullptr, acch,
                                                         nullptr, nullptr, nullptr, nullptr, N);
  ptag64_k<false, false, false><<<g16, 256, 0, stream>>>(ptr, ep, hb1, hb0, W2k(0,3), nullptr, acch,
                                                         nullptr, nullptr, nullptr, nullptr, N);
  ptag64_k<false, true,  false><<<g16, 256, 0, stream>>>(ptr, ep, hb0, hb2, W2k(0,4), nullptr, acch,
                                                         (const float4*)b2, nullptr, nullptr, nullptr, N);
  ptag64_k<true,  false, false><<<g16, 256, 0, stream>>>(ptr, ep, hb2, hb0, W2k(1,1), W2k(1,0), acch,
                                                         nullptr, nullptr, nullptr, nullptr, N);
  ptag64_k<false, false, false><<<g16, 256, 0, stream>>>(ptr, ep, hb0, hb1, W2k(1,2), nullptr, acch,
                                                         nullptr, nullptr, nullptr, nullptr, N);
  ptag64_k<false, false, false><<<g16, 256, 0, stream>>>(ptr, ep, hb1, hb0, W2k(1,3), nullptr, acch,
                                                         nullptr, nullptr, nullptr, nullptr, N);
  ptag64_k<false, true,  true ><<<g16, 256, 0, stream>>>(ptr, ep, hb0, nullptr, W2k(1,4), nullptr, acch,
                                                         (const float4*)(b2 + 64), Wout, bout, out, N);
}